// Round 4
// baseline (342.313 us; speedup 1.0000x reference)
//
#include <hip/hip_runtime.h>
#include <hip/hip_bf16.h>

// ---------------------------------------------------------------------------
// x (N=64, C=256, T=300, V=17) fp32.  Output fp32 same shape.
// v->part: 0-4 -> p0 ; 5,7,9 -> p1 ; 6,8,10 -> p2 ; 11,13,15 -> p3 ; 12,14,16 -> p4
// Pass1 (32x32x16 MFMA): padded row space of 352 rows = 11 tiles of 32:
//   p0:[0,96) 80 real; p1:[96,160) 48; p2:[160,224) 48; p3:[224,288) 48; p4:[288,352) 48
// per (n, 16-t block): GEMM rows x W[p] (64q x 256c), BN+ReLU+mean -> pooled atomics.
// ---------------------------------------------------------------------------

typedef __attribute__((ext_vector_type(8)))  short short8;
typedef __attribute__((ext_vector_type(16))) float f32x16;
typedef float f4u __attribute__((ext_vector_type(4), aligned(4)));

__device__ __forceinline__ unsigned short f2bf(float f) {
    unsigned int u = __float_as_uint(f);
    u = (u + 0x7FFFu + ((u >> 16) & 1u)) >> 16;   // RNE
    return (unsigned short)u;
}

// ---- fold BN params into scale/bias ---------------------------------------
__global__ void fold_kernel(
    const float* __restrict__ part_b, const float* __restrict__ pbn_g,
    const float* __restrict__ pbn_b,  const float* __restrict__ pbn_m,
    const float* __restrict__ pbn_v,
    const float* __restrict__ fc1_b,  const float* __restrict__ fbn_g,
    const float* __restrict__ fbn_b,  const float* __restrict__ fbn_m,
    const float* __restrict__ fbn_v,
    const float* __restrict__ bn_g,   const float* __restrict__ bn_b,
    const float* __restrict__ bn_m,   const float* __restrict__ bn_v,
    float* __restrict__ ps, float* __restrict__ pb,
    float* __restrict__ fs, float* __restrict__ fb,
    float* __restrict__ cs, float* __restrict__ cb)
{
    int tid = threadIdx.x;
    if (tid < 320) {
        float s = pbn_g[tid] * rsqrtf(pbn_v[tid] + 1e-5f);
        ps[tid] = s;
        pb[tid] = part_b[tid] * s + pbn_b[tid] - pbn_m[tid] * s;
    }
    if (tid < 64) {
        float s = fbn_g[tid] * rsqrtf(fbn_v[tid] + 1e-5f);
        fs[tid] = s;
        fb[tid] = fc1_b[tid] * s + fbn_b[tid] - fbn_m[tid] * s;
    }
    if (tid < 256) {
        float s = bn_g[tid] * rsqrtf(bn_v[tid] + 1e-5f);
        cs[tid] = s;
        cb[tid] = bn_b[tid] - bn_m[tid] * s;
    }
}

// ---- convert part_w [5][64][256] fp32 -> bf16 (same layout) ---------------
__global__ void conv_w_kernel(const float* __restrict__ pw, unsigned short* __restrict__ wq)
{
    int i = blockIdx.x * 256 + threadIdx.x;
    if (i < 5 * 64 * 256) wq[i] = f2bf(pw[i]);
}

// ---- pass 1: 32x32x16 MFMA part conv + BN + ReLU + mean-pool --------------
// grid = 64 n * 19 t-chunks; block 256 = 4 waves; wave w owns tiles {3w,3w+1,3w+2<11}.
__global__ __launch_bounds__(256, 3) void part_pool_kernel(
    const float* __restrict__ x, const unsigned short* __restrict__ wq,
    const float* __restrict__ ps, const float* __restrict__ pbs,
    float* __restrict__ pooled)
{
    // padded row for (t=0, v); row(t,v) = ROWC[v] + t*CNTV[v]
    constexpr int ROWC[17] = {0,1,2,3,4, 96,160, 97,161, 98,162, 224,288, 225,289, 226,290};
    constexpr int CNTV[17] = {5,5,5,5,5, 3,3,3,3,3,3, 3,3,3,3,3,3};

    __shared__ short Xs[352 * 64];   // [row][c] bf16, 128B rows, XOR-swizzled: 45056 B

    const int blk  = blockIdx.x;
    const int n    = blk / 19;
    const int tb   = (blk % 19) * 16;
    const int tid  = threadIdx.x;
    const int lane = tid & 63;
    const int wv   = tid >> 6;
    const int l31  = lane & 31;
    const int hi   = lane >> 5;            // k-group 0/1
    const int key  = (l31 & 7) << 4;       // read swizzle key (row&7 == l31&7)

    // wave's tiles (3,3,3,2)
    const int t0 = wv * 3, t1 = wv * 3 + 1, t2k = wv * 3 + 2;
    const bool has2 = (t2k < 11);
    auto PART = [](int t) { return (t < 3) ? 0 : (((t - 3) >> 1) + 1); };
    const int P0 = PART(t0), P1 = PART(t1), P2 = has2 ? PART(t2k) : P1;
    const int pa  = P0;
    const int pbp = (P2 != P0) ? P2 : ((P1 != P0) ? P1 : P0);  // second distinct part (or pa)
    const bool s1 = (P1 != pa);            // tile1 uses slot b?
    const bool s2 = (P2 != pa);

    // staging mapping: c-pair + t-pair per thread
    const int cp  = tid & 31;
    const int oct = tid >> 5;

    f32x16 acc[3][2];
    #pragma unroll
    for (int i = 0; i < 3; ++i)
        #pragma unroll
        for (int qt = 0; qt < 2; ++qt)
            #pragma unroll
            for (int r = 0; r < 16; ++r) acc[i][qt][r] = 0.f;

    for (int cc = 0; cc < 256; cc += 64) {
        __syncthreads();
        // ---- stage x[n, cc+2cp..+1, tb+2oct..+1, 0..16] -> Xs[row][c] bf16
        #pragma unroll
        for (int dt = 0; dt < 2; ++dt) {
            const int tl = 2 * oct + dt;
            const int tg = tb + tl;
            if (tg < 300) {
                const float* g0 = x + ((size_t)(n * 256 + cc + 2 * cp) * 300 + tg) * 17;
                const float* g1 = g0 + 300 * 17;
                float r0[17], r1[17];
                f4u a0 = *(const f4u*)(g0);     f4u b0 = *(const f4u*)(g1);
                f4u a1 = *(const f4u*)(g0 + 4); f4u b1 = *(const f4u*)(g1 + 4);
                f4u a2 = *(const f4u*)(g0 + 8); f4u b2 = *(const f4u*)(g1 + 8);
                f4u a3 = *(const f4u*)(g0 +12); f4u b3 = *(const f4u*)(g1 +12);
                #pragma unroll
                for (int j = 0; j < 4; ++j) {
                    r0[j]    = a0[j]; r1[j]    = b0[j];
                    r0[4+j]  = a1[j]; r1[4+j]  = b1[j];
                    r0[8+j]  = a2[j]; r1[8+j]  = b2[j];
                    r0[12+j] = a3[j]; r1[12+j] = b3[j];
                }
                r0[16] = g0[16]; r1[16] = g1[16];
                #pragma unroll
                for (int v = 0; v < 17; ++v) {
                    const int row = ROWC[v] + tl * CNTV[v];
                    unsigned int pk = (unsigned int)f2bf(r0[v]) | ((unsigned int)f2bf(r1[v]) << 16);
                    const int off = row * 128 + ((cp * 4) ^ ((row & 7) << 4));
                    *(unsigned int*)((char*)Xs + off) = pk;
                }
            }
        }
        __syncthreads();

        // ---- compute: 4 k-steps of 16; A from LDS, B (W) from L2 ----------
        #pragma unroll
        for (int kk = 0; kk < 4; ++kk) {
            const int kbase = cc + kk * 16 + hi * 8;
            short8 Ba0 = *(const short8*)(wq + ((pa  * 64      + l31) << 8) + kbase);
            short8 Ba1 = *(const short8*)(wq + ((pa  * 64 + 32 + l31) << 8) + kbase);
            short8 Bb0 = Ba0, Bb1 = Ba1;
            if (pbp != pa) {
                Bb0 = *(const short8*)(wq + ((pbp * 64      + l31) << 8) + kbase);
                Bb1 = *(const short8*)(wq + ((pbp * 64 + 32 + l31) << 8) + kbase);
            }
            const int coff = kk * 32 + hi * 16;

            short8 A0 = *(const short8*)((const char*)Xs + (t0  * 32 + l31) * 128 + (coff ^ key));
            acc[0][0] = __builtin_amdgcn_mfma_f32_32x32x16_bf16(A0, Ba0, acc[0][0], 0, 0, 0);
            acc[0][1] = __builtin_amdgcn_mfma_f32_32x32x16_bf16(A0, Ba1, acc[0][1], 0, 0, 0);

            short8 A1 = *(const short8*)((const char*)Xs + (t1  * 32 + l31) * 128 + (coff ^ key));
            acc[1][0] = __builtin_amdgcn_mfma_f32_32x32x16_bf16(A1, s1 ? Bb0 : Ba0, acc[1][0], 0, 0, 0);
            acc[1][1] = __builtin_amdgcn_mfma_f32_32x32x16_bf16(A1, s1 ? Bb1 : Ba1, acc[1][1], 0, 0, 0);

            if (has2) {
                short8 A2 = *(const short8*)((const char*)Xs + (t2k * 32 + l31) * 128 + (coff ^ key));
                acc[2][0] = __builtin_amdgcn_mfma_f32_32x32x16_bf16(A2, s2 ? Bb0 : Ba0, acc[2][0], 0, 0, 0);
                acc[2][1] = __builtin_amdgcn_mfma_f32_32x32x16_bf16(A2, s2 ? Bb1 : Ba1, acc[2][1], 0, 0, 0);
            }
        }
    }

    // ---- epilogue: D[row][q]: q = qt*32 + l31, row_in_tile = (r&3)+8*(r>>2)+4*hi
    float sq0 = 0.f, sq1 = 0.f;
    #pragma unroll
    for (int i = 0; i < 3; ++i) {
        if (i == 2 && !has2) break;
        const int tI   = wv * 3 + i;
        const int Pi   = (i == 0) ? P0 : (i == 1 ? P1 : P2);
        const int tip  = (tI < 3) ? tI : ((tI - 3) & 1);
        const int RPp  = (Pi == 0) ? 80 : 48;
        const float mulc = (Pi == 0) ? 0.200000003f : 0.333333343f;   // > 1/cnt
        const float coef = (Pi == 0) ? (1.f / 1500.f) : (1.f / 900.f);
        const float sA = ps [Pi * 64      + l31];
        const float bA = pbs[Pi * 64      + l31];
        const float sB = ps [Pi * 64 + 32 + l31];
        const float bB = pbs[Pi * 64 + 32 + l31];
        #pragma unroll
        for (int r = 0; r < 16; ++r) {
            const int rit = (r & 3) + ((r >> 2) << 3) + (hi << 2);
            const int rip = tip * 32 + rit;
            const int tl  = (int)((float)rip * mulc);
            if (rip < RPp && tb + tl < 300) {
                const float y0 = fmaf(sA, acc[i][0][r], bA);
                sq0 = fmaf(fmaxf(y0, 0.f), coef, sq0);
                const float y1 = fmaf(sB, acc[i][1][r], bB);
                sq1 = fmaf(fmaxf(y1, 0.f), coef, sq1);
            }
        }
    }
    sq0 += __shfl_xor(sq0, 32);
    sq1 += __shfl_xor(sq1, 32);
    const int   qq  = (lane < 32) ? l31 : (32 + l31);
    const float val = (lane < 32) ? sq0 : sq1;
    atomicAdd(&pooled[(n << 6) + qq], val);
}

// ---- pass 2: FC1+BN+ReLU, FC2, softmax over 5 parts -> att[n][c][p] -------
__global__ __launch_bounds__(256) void fc_att_kernel(
    const float* __restrict__ pooled, const float* __restrict__ fc1_w,
    const float* __restrict__ fs, const float* __restrict__ fb,
    const float* __restrict__ fc2_w, const float* __restrict__ fc2_b,
    float* __restrict__ att)
{
    __shared__ float pl[64];
    __shared__ float hl[64];
    const int n = blockIdx.x;
    const int tid = threadIdx.x;

    if (tid < 64) pl[tid] = pooled[(n << 6) + tid];
    __syncthreads();
    if (tid < 64) {
        float d = 0.f;
        #pragma unroll
        for (int j = 0; j < 64; ++j) d = fmaf(pl[j], fc1_w[(tid << 6) + j], d);
        hl[tid] = fmaxf(fmaf(d, fs[tid], fb[tid]), 0.f);
    }
    __syncthreads();

    const int c = tid;  // 0..255
    float z[5];
    #pragma unroll
    for (int p = 0; p < 5; ++p) {
        const float* wrow = fc2_w + ((size_t)(c * 5 + p) << 6);
        float d = fc2_b[c * 5 + p];
        #pragma unroll
        for (int i = 0; i < 64; ++i) d = fmaf(hl[i], wrow[i], d);
        z[p] = d;
    }
    float m = z[0];
    #pragma unroll
    for (int p = 1; p < 5; ++p) m = fmaxf(m, z[p]);
    float e[5], ssum = 0.f;
    #pragma unroll
    for (int p = 0; p < 5; ++p) { e[p] = __expf(z[p] - m); ssum += e[p]; }
    const float inv = 1.f / ssum;
    #pragma unroll
    for (int p = 0; p < 5; ++p)
        att[((size_t)((n << 8) + c)) * 5 + p] = e[p] * inv;
}

// ---- pass 3: out = relu( x*(att*cs + 1) + cb ), float4 vectorized ---------
__global__ __launch_bounds__(256) void apply_att_kernel(
    const float* __restrict__ x, const float* __restrict__ att,
    const float* __restrict__ cs, const float* __restrict__ cb,
    float* __restrict__ out)
{
    __shared__ float mult[17];
    const int nc  = blockIdx.x;          // n*256 + c
    const int c   = nc & 255;
    const int tid = threadIdx.x;

    if (tid < 17) {
        const int v = tid;
        const int p = (v < 5) ? 0 : ((v < 11) ? (2 - (v & 1)) : (4 - (v & 1)));
        mult[v] = fmaf(att[(size_t)nc * 5 + p], cs[c], 1.0f);
    }
    __syncthreads();

    const float cbc = cb[c];
    const float4* xp = (const float4*)(x + (size_t)nc * 5100);
    float4* op = (float4*)(out + (size_t)nc * 5100);

    for (int f = tid; f < 1275; f += 256) {
        float4 xv = xp[f];
        const int v0 = (4 * f) % 17;
        float o[4];
        const float xi[4] = {xv.x, xv.y, xv.z, xv.w};
        #pragma unroll
        for (int j = 0; j < 4; ++j) {
            int vj = v0 + j; if (vj >= 17) vj -= 17;
            o[j] = fmaxf(fmaf(xi[j], mult[vj], cbc), 0.f);
        }
        float4 ov; ov.x = o[0]; ov.y = o[1]; ov.z = o[2]; ov.w = o[3];
        op[f] = ov;
    }
}

// ---------------------------------------------------------------------------
extern "C" void kernel_launch(void* const* d_in, const int* in_sizes, int n_in,
                              void* d_out, int out_size, void* d_ws, size_t ws_size,
                              hipStream_t stream)
{
    const float* x      = (const float*)d_in[0];
    const float* part_w = (const float*)d_in[1];
    const float* part_b = (const float*)d_in[2];
    const float* pbn_g  = (const float*)d_in[3];
    const float* pbn_b  = (const float*)d_in[4];
    const float* pbn_m  = (const float*)d_in[5];
    const float* pbn_v  = (const float*)d_in[6];
    const float* fc1_w  = (const float*)d_in[7];
    const float* fc1_b  = (const float*)d_in[8];
    const float* fbn_g  = (const float*)d_in[9];
    const float* fbn_b  = (const float*)d_in[10];
    const float* fbn_m  = (const float*)d_in[11];
    const float* fbn_v  = (const float*)d_in[12];
    const float* fc2_w  = (const float*)d_in[13];
    const float* fc2_b  = (const float*)d_in[14];
    const float* bn_g   = (const float*)d_in[15];
    const float* bn_b   = (const float*)d_in[16];
    const float* bn_m   = (const float*)d_in[17];
    const float* bn_v   = (const float*)d_in[18];

    float* ws     = (float*)d_ws;
    float* pooled = ws;             // 4096
    float* att    = ws + 4096;      // 81920
    float* ps     = ws + 86016;     // 320
    float* pbias  = ws + 86336;     // 320
    float* fs     = ws + 86656;     // 64
    float* fb     = ws + 86720;     // 64
    float* cs     = ws + 86784;     // 256
    float* cb     = ws + 87040;     // 256
    unsigned short* wq = (unsigned short*)(ws + 87296);  // 81920 bf16 (16B-aligned)

    hipMemsetAsync(pooled, 0, 4096 * sizeof(float), stream);

    fold_kernel<<<1, 320, 0, stream>>>(part_b, pbn_g, pbn_b, pbn_m, pbn_v,
                                       fc1_b, fbn_g, fbn_b, fbn_m, fbn_v,
                                       bn_g, bn_b, bn_m, bn_v,
                                       ps, pbias, fs, fb, cs, cb);
    conv_w_kernel<<<320, 256, 0, stream>>>(part_w, wq);
    part_pool_kernel<<<64 * 19, 256, 0, stream>>>(x, wq, ps, pbias, pooled);
    fc_att_kernel<<<64, 256, 0, stream>>>(pooled, fc1_w, fs, fb, fc2_w, fc2_b, att);
    apply_att_kernel<<<16384, 256, 0, stream>>>(x, att, cs, cb, (float*)d_out);
}

// Round 5
// 285.703 us; speedup vs baseline: 1.1981x; 1.1981x over previous
//
#include <hip/hip_runtime.h>
#include <hip/hip_bf16.h>

// ---------------------------------------------------------------------------
// x (N=64, C=256, T=300, V=17) fp32.  Output fp32 same shape.
// v->part: 0-4 -> p0 ; 5,7,9 -> p1 ; 6,8,10 -> p2 ; 11,13,15 -> p3 ; 12,14,16 -> p4
// Pass1: per (n, 16-t block): 272 (t,v) rows grouped by part into 17 tiles of 16;
// GEMM vs W[p] (64q x 256c) via mfma_f32_16x16x32_bf16, K chunked by 32 with a
// coalesced global->native->transposed LDS bounce. BN+ReLU+mean -> pooled atomics.
// ---------------------------------------------------------------------------

typedef __attribute__((ext_vector_type(8))) short short8;
typedef __attribute__((ext_vector_type(4))) float f32x4;
typedef float f4u __attribute__((ext_vector_type(4), aligned(4)));

__device__ __forceinline__ unsigned short f2bf(float f) {
    unsigned int u = __float_as_uint(f);
    u = (u + 0x7FFFu + ((u >> 16) & 1u)) >> 16;   // RNE
    return (unsigned short)u;
}

// ---- fold BN params into scale/bias ---------------------------------------
__global__ void fold_kernel(
    const float* __restrict__ part_b, const float* __restrict__ pbn_g,
    const float* __restrict__ pbn_b,  const float* __restrict__ pbn_m,
    const float* __restrict__ pbn_v,
    const float* __restrict__ fc1_b,  const float* __restrict__ fbn_g,
    const float* __restrict__ fbn_b,  const float* __restrict__ fbn_m,
    const float* __restrict__ fbn_v,
    const float* __restrict__ bn_g,   const float* __restrict__ bn_b,
    const float* __restrict__ bn_m,   const float* __restrict__ bn_v,
    float* __restrict__ ps, float* __restrict__ pb,
    float* __restrict__ fs, float* __restrict__ fb,
    float* __restrict__ cs, float* __restrict__ cb)
{
    int tid = threadIdx.x;
    if (tid < 320) {
        float s = pbn_g[tid] * rsqrtf(pbn_v[tid] + 1e-5f);
        ps[tid] = s;
        pb[tid] = part_b[tid] * s + pbn_b[tid] - pbn_m[tid] * s;
    }
    if (tid < 64) {
        float s = fbn_g[tid] * rsqrtf(fbn_v[tid] + 1e-5f);
        fs[tid] = s;
        fb[tid] = fc1_b[tid] * s + fbn_b[tid] - fbn_m[tid] * s;
    }
    if (tid < 256) {
        float s = bn_g[tid] * rsqrtf(bn_v[tid] + 1e-5f);
        cs[tid] = s;
        cb[tid] = bn_b[tid] - bn_m[tid] * s;
    }
}

// ---- part_w [5][64][256] fp32 -> bf16 fragment-major ----------------------
// out[(((p*8+kc)*4+wv)*4+g)*16 + r15][8] so a wave's B-load is one coalesced b128.
__global__ void conv_w_kernel(const float* __restrict__ pw, unsigned short* __restrict__ wq2)
{
    int i = blockIdx.x * 256 + threadIdx.x;
    if (i < 5 * 64 * 256) {
        int p = i >> 14;
        int q = (i >> 8) & 63;
        int c = i & 255;
        int kc = c >> 5, g = (c >> 3) & 3, j = c & 7;
        int wv = q >> 4, r15 = q & 15;
        wq2[((((p * 8 + kc) * 4 + wv) * 4 + g) * 16 + r15) * 8 + j] = f2bf(pw[i]);
    }
}

// ---- pass 1: 16x16x32 MFMA with coalesced two-stage LDS bounce ------------
// grid = 64 n * 19 t-chunks; block 256 = 4 waves; wave wv owns q-tile wv.
__global__ __launch_bounds__(256, 3) void part_pool_kernel(
    const float* __restrict__ x, const unsigned short* __restrict__ wq2,
    const float* __restrict__ ps, const float* __restrict__ pbs,
    float* __restrict__ pooled)
{
    constexpr int PMAP[17] = {0,0,0,0,0, 1,1,1, 2,2,2, 3,3,3, 4,4,4};
    constexpr int BASE[5]  = {0,80,128,176,224};
    constexpr int CNT[5]   = {5,3,3,3,3};
    constexpr float COEF[5] = {1.f/1500.f, 1.f/900.f, 1.f/900.f, 1.f/900.f, 1.f/900.f};

    __shared__ short Xn[32 * 272];           // native [c][f] bf16: 17408 B
    __shared__ short Xt[272 * 32];           // transposed [row][c] bf16, 64-B rows, swizzled
    __shared__ unsigned short rows4[68][4];  // row(4q+j) table

    const int tid  = threadIdx.x;
    const int lane = tid & 63;
    const int wv   = tid >> 6;
    const int r15  = lane & 15;
    const int g    = lane >> 4;

    const int blk = blockIdx.x;
    const int n   = blk / 19;
    const int tb  = (blk % 19) * 16;
    const bool tail = (tb + 16 > 300);

    // build row table: f = 4q+j -> row (part-grouped)
    if (tid < 68) {
        #pragma unroll
        for (int j = 0; j < 4; ++j) {
            const int f = 4 * tid + j;
            const int t = (int)(((unsigned)f * 61681u) >> 20);   // f/17, f<272
            const int v = f - 17 * t;
            int row;
            if (v < 5)        row = v + 5 * t;
            else if (v < 11)  row = ((v & 1) ? (80 + ((v - 5) >> 1)) : (128 + ((v - 6) >> 1))) + 3 * t;
            else              row = ((v & 1) ? (176 + ((v - 11) >> 1)) : (224 + ((v - 12) >> 1))) + 3 * t;
            rows4[tid][j] = (unsigned short)row;
        }
    }

    f32x4 acc[17];
    #pragma unroll
    for (int m = 0; m < 17; ++m) acc[m] = (f32x4){0.f, 0.f, 0.f, 0.f};

    const size_t xbase = (size_t)n * 1305600 + (size_t)tb * 17;

    for (int cc = 0; cc < 256; cc += 32) {
        __syncthreads();   // Xn free (prev S2 done), rows4 ready, Xt free (prev COMP done)

        // ---- S1: coalesced global float4 -> bf16 pack -> native [c][f] ----
        #pragma unroll
        for (int it = 0; it < 9; ++it) {
            const int pi = it * 256 + tid;
            if (pi < 2176) {
                const int c = (int)(((unsigned)pi * 61681u) >> 22);   // pi/68
                const int q = pi - 68 * c;
                const float* gp = x + xbase + (size_t)(cc + c) * 5100 + 4 * q;
                unsigned int lo, hi2;
                if (!tail) {
                    f4u xv = *(const f4u*)gp;
                    lo  = (unsigned int)f2bf(xv[0]) | ((unsigned int)f2bf(xv[1]) << 16);
                    hi2 = (unsigned int)f2bf(xv[2]) | ((unsigned int)f2bf(xv[3]) << 16);
                } else {
                    float e[4];
                    #pragma unroll
                    for (int j = 0; j < 4; ++j) {
                        const int f = 4 * q + j;
                        const int t = (int)(((unsigned)f * 61681u) >> 20);
                        e[j] = 0.f;
                        if (tb + t < 300) e[j] = gp[j];
                    }
                    lo  = (unsigned int)f2bf(e[0]) | ((unsigned int)f2bf(e[1]) << 16);
                    hi2 = (unsigned int)f2bf(e[2]) | ((unsigned int)f2bf(e[3]) << 16);
                }
                *(uint2*)&Xn[c * 272 + 4 * q] = make_uint2(lo, hi2);
            }
        }
        __syncthreads();

        // ---- S2: LDS transpose native -> Xt[row][c], XOR-swizzled ---------
        #pragma unroll
        for (int it = 0; it < 5; ++it) {
            const int pi = it * 256 + tid;
            if (pi < 1088) {
                const int cp = (int)(((unsigned)pi * 61681u) >> 22);  // pi/68 (c-pair)
                const int q  = pi - 68 * cp;
                const uint2 a = *(const uint2*)&Xn[(2 * cp)     * 272 + 4 * q];
                const uint2 b = *(const uint2*)&Xn[(2 * cp + 1) * 272 + 4 * q];
                unsigned int w[4];
                w[0] = (a.x & 0xFFFFu) | (b.x << 16);
                w[1] = (a.x >> 16)     | (b.x & 0xFFFF0000u);
                w[2] = (a.y & 0xFFFFu) | (b.y << 16);
                w[3] = (a.y >> 16)     | (b.y & 0xFFFF0000u);
                const ushort4 rq = *(const ushort4*)&rows4[q][0];
                const int rr[4] = {rq.x, rq.y, rq.z, rq.w};
                #pragma unroll
                for (int j = 0; j < 4; ++j) {
                    const int row = rr[j];
                    const int off = row * 64 + ((cp * 4) ^ (((row >> 1) & 3) << 4));
                    *(unsigned int*)((char*)Xt + off) = w[j];
                }
            }
        }
        __syncthreads();

        // ---- COMP: one K=32 step; A from Xt, B coalesced from L2 ----------
        const int kc = cc >> 5;
        short8 bfr[5];
        #pragma unroll
        for (int p = 0; p < 5; ++p)
            bfr[p] = *(const short8*)(wq2 + ((((p * 8 + kc) * 4 + wv) * 4 + g) * 16 + r15) * 8);

        #pragma unroll
        for (int m = 0; m < 17; ++m) {
            const int row = m * 16 + r15;
            const int off = row * 64 + ((g * 16) ^ (((row >> 1) & 3) << 4));
            short8 A = *(const short8*)((const char*)Xt + off);
            acc[m] = __builtin_amdgcn_mfma_f32_16x16x32_bf16(A, bfr[PMAP[m]], acc[m], 0, 0, 0);
        }
    }

    // ---- epilogue: D[row][q]: col q = wv*16 + r15, row = m*16 + g*4 + rg --
    const int q = wv * 16 + r15;
    float s5[5], b5[5];
    #pragma unroll
    for (int p = 0; p < 5; ++p) { s5[p] = ps[(p << 6) + q]; b5[p] = pbs[(p << 6) + q]; }

    float sum = 0.f;
    #pragma unroll
    for (int m = 0; m < 17; ++m) {
        const int p = PMAP[m];
        #pragma unroll
        for (int rg = 0; rg < 4; ++rg) {
            const int row = m * 16 + g * 4 + rg;
            const int tl  = (row - BASE[p]) / CNT[p];
            if (tb + tl < 300) {
                float y = fmaf(s5[p], acc[m][rg], b5[p]);
                sum = fmaf(fmaxf(y, 0.f), COEF[p], sum);
            }
        }
    }
    sum += __shfl_xor(sum, 16);
    sum += __shfl_xor(sum, 32);
    if (g == 0) atomicAdd(&pooled[(n << 6) + q], sum);
}

// ---- pass 2: FC1+BN+ReLU, FC2, softmax over 5 parts -> att[n][c][p] -------
__global__ __launch_bounds__(256) void fc_att_kernel(
    const float* __restrict__ pooled, const float* __restrict__ fc1_w,
    const float* __restrict__ fs, const float* __restrict__ fb,
    const float* __restrict__ fc2_w, const float* __restrict__ fc2_b,
    float* __restrict__ att)
{
    __shared__ float pl[64];
    __shared__ float hl[64];
    const int n = blockIdx.x;
    const int tid = threadIdx.x;

    if (tid < 64) pl[tid] = pooled[(n << 6) + tid];
    __syncthreads();
    if (tid < 64) {
        float d = 0.f;
        #pragma unroll
        for (int j = 0; j < 64; ++j) d = fmaf(pl[j], fc1_w[(tid << 6) + j], d);
        hl[tid] = fmaxf(fmaf(d, fs[tid], fb[tid]), 0.f);
    }
    __syncthreads();

    const int c = tid;  // 0..255
    float z[5];
    #pragma unroll
    for (int p = 0; p < 5; ++p) {
        const float* wrow = fc2_w + ((size_t)(c * 5 + p) << 6);
        float d = fc2_b[c * 5 + p];
        #pragma unroll
        for (int i = 0; i < 64; ++i) d = fmaf(hl[i], wrow[i], d);
        z[p] = d;
    }
    float m = z[0];
    #pragma unroll
    for (int p = 1; p < 5; ++p) m = fmaxf(m, z[p]);
    float e[5], ssum = 0.f;
    #pragma unroll
    for (int p = 0; p < 5; ++p) { e[p] = __expf(z[p] - m); ssum += e[p]; }
    const float inv = 1.f / ssum;
    #pragma unroll
    for (int p = 0; p < 5; ++p)
        att[((size_t)((n << 8) + c)) * 5 + p] = e[p] * inv;
}

// ---- pass 3: out = relu( x*(att*cs + 1) + cb ), float4 vectorized ---------
__global__ __launch_bounds__(256) void apply_att_kernel(
    const float* __restrict__ x, const float* __restrict__ att,
    const float* __restrict__ cs, const float* __restrict__ cb,
    float* __restrict__ out)
{
    __shared__ float mult[17];
    const int nc  = blockIdx.x;          // n*256 + c
    const int c   = nc & 255;
    const int tid = threadIdx.x;

    if (tid < 17) {
        const int v = tid;
        const int p = (v < 5) ? 0 : ((v < 11) ? (2 - (v & 1)) : (4 - (v & 1)));
        mult[v] = fmaf(att[(size_t)nc * 5 + p], cs[c], 1.0f);
    }
    __syncthreads();

    const float cbc = cb[c];
    const float4* xp = (const float4*)(x + (size_t)nc * 5100);
    float4* op = (float4*)(out + (size_t)nc * 5100);

    for (int f = tid; f < 1275; f += 256) {
        float4 xv = xp[f];
        const int v0 = (4 * f) % 17;
        float o[4];
        const float xi[4] = {xv.x, xv.y, xv.z, xv.w};
        #pragma unroll
        for (int j = 0; j < 4; ++j) {
            int vj = v0 + j; if (vj >= 17) vj -= 17;
            o[j] = fmaxf(fmaf(xi[j], mult[vj], cbc), 0.f);
        }
        float4 ov; ov.x = o[0]; ov.y = o[1]; ov.z = o[2]; ov.w = o[3];
        op[f] = ov;
    }
}

// ---------------------------------------------------------------------------
extern "C" void kernel_launch(void* const* d_in, const int* in_sizes, int n_in,
                              void* d_out, int out_size, void* d_ws, size_t ws_size,
                              hipStream_t stream)
{
    const float* x      = (const float*)d_in[0];
    const float* part_w = (const float*)d_in[1];
    const float* part_b = (const float*)d_in[2];
    const float* pbn_g  = (const float*)d_in[3];
    const float* pbn_b  = (const float*)d_in[4];
    const float* pbn_m  = (const float*)d_in[5];
    const float* pbn_v  = (const float*)d_in[6];
    const float* fc1_w  = (const float*)d_in[7];
    const float* fc1_b  = (const float*)d_in[8];
    const float* fbn_g  = (const float*)d_in[9];
    const float* fbn_b  = (const float*)d_in[10];
    const float* fbn_m  = (const float*)d_in[11];
    const float* fbn_v  = (const float*)d_in[12];
    const float* fc2_w  = (const float*)d_in[13];
    const float* fc2_b  = (const float*)d_in[14];
    const float* bn_g   = (const float*)d_in[15];
    const float* bn_b   = (const float*)d_in[16];
    const float* bn_m   = (const float*)d_in[17];
    const float* bn_v   = (const float*)d_in[18];

    float* ws     = (float*)d_ws;
    float* pooled = ws;             // 4096
    float* att    = ws + 4096;      // 81920
    float* ps     = ws + 86016;     // 320
    float* pbias  = ws + 86336;     // 320
    float* fs     = ws + 86656;     // 64
    float* fb     = ws + 86720;     // 64
    float* cs     = ws + 86784;     // 256
    float* cb     = ws + 87040;     // 256
    unsigned short* wq2 = (unsigned short*)(ws + 87296);  // 81920 bf16 fragment-major

    hipMemsetAsync(pooled, 0, 4096 * sizeof(float), stream);

    fold_kernel<<<1, 320, 0, stream>>>(part_b, pbn_g, pbn_b, pbn_m, pbn_v,
                                       fc1_b, fbn_g, fbn_b, fbn_m, fbn_v,
                                       bn_g, bn_b, bn_m, bn_v,
                                       ps, pbias, fs, fb, cs, cb);
    conv_w_kernel<<<320, 256, 0, stream>>>(part_w, wq2);
    part_pool_kernel<<<64 * 19, 256, 0, stream>>>(x, wq2, ps, pbias, pooled);
    fc_att_kernel<<<64, 256, 0, stream>>>(pooled, fc1_w, fs, fb, fc2_w, fc2_b, att);
    apply_att_kernel<<<16384, 256, 0, stream>>>(x, att, cs, cb, (float*)d_out);
}

// Round 6
// 242.192 us; speedup vs baseline: 1.4134x; 1.1797x over previous
//
#include <hip/hip_runtime.h>
#include <hip/hip_bf16.h>

// ---------------------------------------------------------------------------
// x (N=64, C=256, T=300, V=17) fp32.  Output fp32 same shape.
// v->part: 0-4 -> p0 ; 5,7,9 -> p1 ; 6,8,10 -> p2 ; 11,13,15 -> p3 ; 12,14,16 -> p4
// Pass1: per (n, 16-t chunk): 272 (t,v) rows grouped by part into 17 tiles of 16;
// GEMM vs W[p] (64q x 256c) via mfma_f32_16x16x32_bf16.  Software-pipelined:
// global loads for K-chunk k+1 stay in REGISTERS across COMP(k-1) (no vmcnt
// drain at barriers -- raw s_barrier + lgkmcnt(0) only).  BN+ReLU+mean ->
// pooled atomics.
// ---------------------------------------------------------------------------

typedef __attribute__((ext_vector_type(8))) short short8;
typedef __attribute__((ext_vector_type(4))) float f32x4;
typedef float f4a __attribute__((ext_vector_type(4), aligned(16)));

__device__ __forceinline__ unsigned short f2bf(float f) {
    unsigned int u = __float_as_uint(f);
    u = (u + 0x7FFFu + ((u >> 16) & 1u)) >> 16;   // RNE
    return (unsigned short)u;
}

// ---- fold BN params into scale/bias ---------------------------------------
__global__ void fold_kernel(
    const float* __restrict__ part_b, const float* __restrict__ pbn_g,
    const float* __restrict__ pbn_b,  const float* __restrict__ pbn_m,
    const float* __restrict__ pbn_v,
    const float* __restrict__ fc1_b,  const float* __restrict__ fbn_g,
    const float* __restrict__ fbn_b,  const float* __restrict__ fbn_m,
    const float* __restrict__ fbn_v,
    const float* __restrict__ bn_g,   const float* __restrict__ bn_b,
    const float* __restrict__ bn_m,   const float* __restrict__ bn_v,
    float* __restrict__ ps, float* __restrict__ pb,
    float* __restrict__ fs, float* __restrict__ fb,
    float* __restrict__ cs, float* __restrict__ cb)
{
    int tid = threadIdx.x;
    if (tid < 320) {
        float s = pbn_g[tid] * rsqrtf(pbn_v[tid] + 1e-5f);
        ps[tid] = s;
        pb[tid] = part_b[tid] * s + pbn_b[tid] - pbn_m[tid] * s;
    }
    if (tid < 64) {
        float s = fbn_g[tid] * rsqrtf(fbn_v[tid] + 1e-5f);
        fs[tid] = s;
        fb[tid] = fc1_b[tid] * s + fbn_b[tid] - fbn_m[tid] * s;
    }
    if (tid < 256) {
        float s = bn_g[tid] * rsqrtf(bn_v[tid] + 1e-5f);
        cs[tid] = s;
        cb[tid] = bn_b[tid] - bn_m[tid] * s;
    }
}

// ---- part_w [5][64][256] fp32 -> bf16 fragment-major ----------------------
// out[(((p*8+kc)*4+wv)*4+g)*16 + r15][8] so a wave's B-load is one coalesced b128.
__global__ void conv_w_kernel(const float* __restrict__ pw, unsigned short* __restrict__ wq2)
{
    int i = blockIdx.x * 256 + threadIdx.x;
    if (i < 5 * 64 * 256) {
        int p = i >> 14;
        int q = (i >> 8) & 63;
        int c = i & 255;
        int kc = c >> 5, g = (c >> 3) & 3, j = c & 7;
        int wv = q >> 4, r15 = q & 15;
        wq2[((((p * 8 + kc) * 4 + wv) * 4 + g) * 16 + r15) * 8 + j] = f2bf(pw[i]);
    }
}

// ---- pass 1: pipelined 16x16x32 MFMA part conv + BN + ReLU + mean-pool ----
// grid = 64 n * 19 t-chunks; block 256 = 4 waves; wave wv owns q-tile wv.
__global__ __launch_bounds__(256, 3) void part_pool_kernel(
    const float* __restrict__ x, const unsigned short* __restrict__ wq2,
    const float* __restrict__ ps, const float* __restrict__ pbs,
    float* __restrict__ pooled)
{
    constexpr int PMAP[17] = {0,0,0,0,0, 1,1,1, 2,2,2, 3,3,3, 4,4,4};
    constexpr int BASE[5]  = {0,80,128,176,224};
    constexpr int CNT[5]   = {5,3,3,3,3};
    constexpr float COEF[5] = {1.f/1500.f, 1.f/900.f, 1.f/900.f, 1.f/900.f, 1.f/900.f};

    __shared__ short Xt[2 * 272 * 32];       // double-buffered [row][32c] bf16, swizzled
    __shared__ unsigned short rows4[68][4];  // row(4*fq+j) table

    const int tid  = threadIdx.x;
    const int lane = tid & 63;
    const int wv   = tid >> 6;
    const int r15  = lane & 15;
    const int g    = lane >> 4;

    const int blk = blockIdx.x;
    const int n   = blk / 19;
    const int tb  = blk % 19;                // t-chunk index, t in [tb*16, tb*16+16)
    const int fqmax = (tb == 18) ? 51 : 68;  // 51*4 = 204 = 12t*17v valid in tail

    // build row table: f = 4*fq+j -> part-grouped row
    if (tid < 68) {
        #pragma unroll
        for (int j = 0; j < 4; ++j) {
            const int f = 4 * tid + j;
            const int t = (int)(((unsigned)f * 61681u) >> 20);   // f/17, f<272
            const int v = f - 17 * t;
            int row;
            if (v < 5)        row = v + 5 * t;
            else if (v < 11)  row = ((v & 1) ? (80 + ((v - 5) >> 1)) : (128 + ((v - 6) >> 1))) + 3 * t;
            else              row = ((v & 1) ? (176 + ((v - 11) >> 1)) : (224 + ((v - 12) >> 1))) + 3 * t;
            rows4[tid][j] = (unsigned short)row;
        }
    }
    __syncthreads();   // publish rows4 (full sync OK, nothing in flight)

    f32x4 acc[17];
    #pragma unroll
    for (int m = 0; m < 17; ++m) acc[m] = (f32x4){0.f, 0.f, 0.f, 0.f};

    const size_t xrow = (size_t)n * 1305600 + (size_t)tb * 272;   // floats

    // per-chunk load slots: 1088 = 16 c-pairs * 68 f4; thread handles 5 slots
    f4a la[5], lb[5];

    #define SLOTVARS(i) \
        const int slot = (i) * 256 + tid; \
        const int cp   = (int)((((unsigned)(slot >> 2)) * 61681u) >> 20); \
        const int fq   = slot - 68 * cp; \
        const bool ok  = (slot < 1088) && (fq < fqmax);

    #define ISSUE(k) { \
        const int cc_ = (k) * 32; \
        _Pragma("unroll") \
        for (int i = 0; i < 5; ++i) { \
            SLOTVARS(i) \
            if (ok) { \
                const float* g0 = x + xrow + (size_t)(cc_ + 2 * cp) * 5100 + 4 * fq; \
                la[i] = *(const f4a*)g0; \
                lb[i] = *(const f4a*)(g0 + 5100); \
            } \
        } }

    #define S1W(k) { \
        char* xbuf = (char*)Xt + ((k) & 1) * 17408; \
        _Pragma("unroll") \
        for (int i = 0; i < 5; ++i) { \
            SLOTVARS(i) \
            if (ok) { \
                const ushort4 rq = *(const ushort4*)&rows4[fq][0]; \
                const int rr[4] = {rq.x, rq.y, rq.z, rq.w}; \
                _Pragma("unroll") \
                for (int j = 0; j < 4; ++j) { \
                    const unsigned int pk = (unsigned int)f2bf(la[i][j]) \
                                          | ((unsigned int)f2bf(lb[i][j]) << 16); \
                    const int row = rr[j]; \
                    const int off = row * 64 + ((cp * 4) ^ (((row >> 1) & 3) << 4)); \
                    *(unsigned int*)(xbuf + off) = pk; \
                } \
            } \
        } }

    short8 wfr[5];
    #define WFETCH(k) { \
        _Pragma("unroll") \
        for (int p = 0; p < 5; ++p) \
            wfr[p] = *(const short8*)(wq2 + ((((p * 8 + (k)) * 4 + wv) * 4 + g) * 16 + r15) * 8); \
        }

    #define COMP(k) { \
        const char* xbuf = (const char*)Xt + ((k) & 1) * 17408; \
        _Pragma("unroll") \
        for (int m = 0; m < 17; ++m) { \
            const int row = m * 16 + r15; \
            const int off = row * 64 + ((g * 16) ^ (((row >> 1) & 3) << 4)); \
            short8 A = *(const short8*)(xbuf + off); \
            acc[m] = __builtin_amdgcn_mfma_f32_16x16x32_bf16(A, wfr[PMAP[m]], acc[m], 0, 0, 0); \
        } }

    ISSUE(0);
    for (int k = 0; k <= 8; ++k) {
        if (k <= 7) S1W(k);                   // consume la/lb -> LDS (buffer k&1)
        if (k >= 1) WFETCH(k - 1);            // W loads issued BEFORE next x batch
        if (k <= 6) ISSUE(k + 1);             // prefetch: in flight across COMP
        asm volatile("s_waitcnt lgkmcnt(0)" ::: "memory");  // publish LDS writes only
        __builtin_amdgcn_s_barrier();
        __builtin_amdgcn_sched_barrier(0);
        if (k >= 1) COMP(k - 1);              // MFMA on buffer (k-1)&1
        __builtin_amdgcn_s_barrier();         // COMP reads done before next S1W reuse
        __builtin_amdgcn_sched_barrier(0);
    }

    // ---- epilogue: D[row][q]: col q = wv*16 + r15, row = m*16 + g*4 + rg --
    const int q = wv * 16 + r15;
    const int tbt = tb * 16;
    float s5[5], b5[5];
    #pragma unroll
    for (int p = 0; p < 5; ++p) { s5[p] = ps[(p << 6) + q]; b5[p] = pbs[(p << 6) + q]; }

    float sum = 0.f;
    #pragma unroll
    for (int m = 0; m < 17; ++m) {
        const int p = PMAP[m];
        #pragma unroll
        for (int rg = 0; rg < 4; ++rg) {
            const int row = m * 16 + g * 4 + rg;
            const int tl  = (row - BASE[p]) / CNT[p];
            if (tbt + tl < 300) {
                float y = fmaf(s5[p], acc[m][rg], b5[p]);
                sum = fmaf(fmaxf(y, 0.f), COEF[p], sum);
            }
        }
    }
    sum += __shfl_xor(sum, 16);
    sum += __shfl_xor(sum, 32);
    if (g == 0) atomicAdd(&pooled[(n << 6) + q], sum);
}

// ---- pass 2: FC1+BN+ReLU, FC2, softmax over 5 parts -> att[n][c][p] -------
__global__ __launch_bounds__(256) void fc_att_kernel(
    const float* __restrict__ pooled, const float* __restrict__ fc1_w,
    const float* __restrict__ fs, const float* __restrict__ fb,
    const float* __restrict__ fc2_w, const float* __restrict__ fc2_b,
    float* __restrict__ att)
{
    __shared__ float pl[64];
    __shared__ float hl[64];
    const int n = blockIdx.x;
    const int tid = threadIdx.x;

    if (tid < 64) pl[tid] = pooled[(n << 6) + tid];
    __syncthreads();
    if (tid < 64) {
        float d = 0.f;
        #pragma unroll
        for (int j = 0; j < 64; ++j) d = fmaf(pl[j], fc1_w[(tid << 6) + j], d);
        hl[tid] = fmaxf(fmaf(d, fs[tid], fb[tid]), 0.f);
    }
    __syncthreads();

    const int c = tid;  // 0..255
    float z[5];
    #pragma unroll
    for (int p = 0; p < 5; ++p) {
        const float* wrow = fc2_w + ((size_t)(c * 5 + p) << 6);
        float d = fc2_b[c * 5 + p];
        #pragma unroll
        for (int i = 0; i < 64; ++i) d = fmaf(hl[i], wrow[i], d);
        z[p] = d;
    }
    float m = z[0];
    #pragma unroll
    for (int p = 1; p < 5; ++p) m = fmaxf(m, z[p]);
    float e[5], ssum = 0.f;
    #pragma unroll
    for (int p = 0; p < 5; ++p) { e[p] = __expf(z[p] - m); ssum += e[p]; }
    const float inv = 1.f / ssum;
    #pragma unroll
    for (int p = 0; p < 5; ++p)
        att[((size_t)((n << 8) + c)) * 5 + p] = e[p] * inv;
}

// ---- pass 3: out = relu( x*(att*cs + 1) + cb ), float4 vectorized ---------
__global__ __launch_bounds__(256) void apply_att_kernel(
    const float* __restrict__ x, const float* __restrict__ att,
    const float* __restrict__ cs, const float* __restrict__ cb,
    float* __restrict__ out)
{
    __shared__ float mult[17];
    const int nc  = blockIdx.x;          // n*256 + c
    const int c   = nc & 255;
    const int tid = threadIdx.x;

    if (tid < 17) {
        const int v = tid;
        const int p = (v < 5) ? 0 : ((v < 11) ? (2 - (v & 1)) : (4 - (v & 1)));
        mult[v] = fmaf(att[(size_t)nc * 5 + p], cs[c], 1.0f);
    }
    __syncthreads();

    const float cbc = cb[c];
    const float4* xp = (const float4*)(x + (size_t)nc * 5100);
    float4* op = (float4*)(out + (size_t)nc * 5100);

    for (int f = tid; f < 1275; f += 256) {
        float4 xv = xp[f];
        const int v0 = (4 * f) % 17;
        float o[4];
        const float xi[4] = {xv.x, xv.y, xv.z, xv.w};
        #pragma unroll
        for (int j = 0; j < 4; ++j) {
            int vj = v0 + j; if (vj >= 17) vj -= 17;
            o[j] = fmaxf(fmaf(xi[j], mult[vj], cbc), 0.f);
        }
        float4 ov; ov.x = o[0]; ov.y = o[1]; ov.z = o[2]; ov.w = o[3];
        op[f] = ov;
    }
}

// ---------------------------------------------------------------------------
extern "C" void kernel_launch(void* const* d_in, const int* in_sizes, int n_in,
                              void* d_out, int out_size, void* d_ws, size_t ws_size,
                              hipStream_t stream)
{
    const float* x      = (const float*)d_in[0];
    const float* part_w = (const float*)d_in[1];
    const float* part_b = (const float*)d_in[2];
    const float* pbn_g  = (const float*)d_in[3];
    const float* pbn_b  = (const float*)d_in[4];
    const float* pbn_m  = (const float*)d_in[5];
    const float* pbn_v  = (const float*)d_in[6];
    const float* fc1_w  = (const float*)d_in[7];
    const float* fc1_b  = (const float*)d_in[8];
    const float* fbn_g  = (const float*)d_in[9];
    const float* fbn_b  = (const float*)d_in[10];
    const float* fbn_m  = (const float*)d_in[11];
    const float* fbn_v  = (const float*)d_in[12];
    const float* fc2_w  = (const float*)d_in[13];
    const float* fc2_b  = (const float*)d_in[14];
    const float* bn_g   = (const float*)d_in[15];
    const float* bn_b   = (const float*)d_in[16];
    const float* bn_m   = (const float*)d_in[17];
    const float* bn_v   = (const float*)d_in[18];

    float* ws     = (float*)d_ws;
    float* pooled = ws;             // 4096
    float* att    = ws + 4096;      // 81920
    float* ps     = ws + 86016;     // 320
    float* pbias  = ws + 86336;     // 320
    float* fs     = ws + 86656;     // 64
    float* fb     = ws + 86720;     // 64
    float* cs     = ws + 86784;     // 256
    float* cb     = ws + 87040;     // 256
    unsigned short* wq2 = (unsigned short*)(ws + 87296);  // 81920 bf16 fragment-major

    hipMemsetAsync(pooled, 0, 4096 * sizeof(float), stream);

    fold_kernel<<<1, 320, 0, stream>>>(part_b, pbn_g, pbn_b, pbn_m, pbn_v,
                                       fc1_b, fbn_g, fbn_b, fbn_m, fbn_v,
                                       bn_g, bn_b, bn_m, bn_v,
                                       ps, pbias, fs, fb, cs, cb);
    conv_w_kernel<<<320, 256, 0, stream>>>(part_w, wq2);
    part_pool_kernel<<<64 * 19, 256, 0, stream>>>(x, wq2, ps, pbias, pooled);
    fc_att_kernel<<<64, 256, 0, stream>>>(pooled, fc1_w, fs, fb, fc2_w, fc2_b, att);
    apply_att_kernel<<<16384, 256, 0, stream>>>(x, att, cs, cb, (float*)d_out);
}